// Round 1
// baseline (768.992 us; speedup 1.0000x reference)
//
#include <hip/hip_runtime.h>
#include <math.h>

#define NN 50000
#define NE 800000
#define ED 128
#define FD 512

static __device__ __forceinline__ float wave_sum(float x) {
#pragma unroll
  for (int off = 32; off > 0; off >>= 1) x += __shfl_xor(x, off, 64);
  return x;
}

// ---------------- QKV GEMM: out = x @ W_qkv + b, split into q,k,v ----------
// 32 rows/block, 256 threads. tx = col in [0,128), j selects q/k/v.
__global__ __launch_bounds__(256) void k_gemm_qkv(
    const float* __restrict__ X, const float* __restrict__ W,
    const float* __restrict__ B, float* __restrict__ q,
    float* __restrict__ kx, float* __restrict__ v) {
  __shared__ float xs[32][ED];  // 16 KB
  const int row0 = blockIdx.x * 32;
  const int tid = threadIdx.x;
  for (int idx = tid; idx < 32 * ED / 4; idx += 256) {
    int r = idx >> 5, c4 = (idx & 31) << 2;
    float4 val = make_float4(0.f, 0.f, 0.f, 0.f);
    if (row0 + r < NN) val = *(const float4*)&X[(size_t)(row0 + r) * ED + c4];
    *(float4*)&xs[r][c4] = val;
  }
  __syncthreads();
  const int tx = tid & 127, ty = tid >> 7;
  float acc[16][3];
#pragma unroll
  for (int i = 0; i < 16; i++) { acc[i][0] = 0.f; acc[i][1] = 0.f; acc[i][2] = 0.f; }
  for (int k0 = 0; k0 < ED; k0 += 4) {
    float bw[4][3];
#pragma unroll
    for (int u = 0; u < 4; u++) {
      const float* wr = &W[(size_t)(k0 + u) * 384 + tx];
      bw[u][0] = wr[0]; bw[u][1] = wr[128]; bw[u][2] = wr[256];
    }
#pragma unroll
    for (int i = 0; i < 16; i++) {
      float4 a4 = *(const float4*)&xs[ty * 16 + i][k0];
      acc[i][0] = fmaf(a4.x, bw[0][0], acc[i][0]);
      acc[i][1] = fmaf(a4.x, bw[0][1], acc[i][1]);
      acc[i][2] = fmaf(a4.x, bw[0][2], acc[i][2]);
      acc[i][0] = fmaf(a4.y, bw[1][0], acc[i][0]);
      acc[i][1] = fmaf(a4.y, bw[1][1], acc[i][1]);
      acc[i][2] = fmaf(a4.y, bw[1][2], acc[i][2]);
      acc[i][0] = fmaf(a4.z, bw[2][0], acc[i][0]);
      acc[i][1] = fmaf(a4.z, bw[2][1], acc[i][1]);
      acc[i][2] = fmaf(a4.z, bw[2][2], acc[i][2]);
      acc[i][0] = fmaf(a4.w, bw[3][0], acc[i][0]);
      acc[i][1] = fmaf(a4.w, bw[3][1], acc[i][1]);
      acc[i][2] = fmaf(a4.w, bw[3][2], acc[i][2]);
    }
  }
  const float bq = B[tx], bk = B[128 + tx], bv = B[256 + tx];
#pragma unroll
  for (int i = 0; i < 16; i++) {
    int row = row0 + ty * 16 + i;
    if (row < NN) {
      q[(size_t)row * ED + tx] = acc[i][0] + bq;
      kx[(size_t)row * ED + tx] = acc[i][1] + bk;
      v[(size_t)row * ED + tx] = acc[i][2] + bv;
    }
  }
}

// ---------------- CSR build ----------------
__global__ void k_hist(const int* __restrict__ src, int* __restrict__ deg) {
  int e = blockIdx.x * 256 + threadIdx.x;
  if (e < NE) atomicAdd(&deg[src[e]], 1);
}

__global__ void k_scan(const int* __restrict__ deg, int* __restrict__ row_start) {
  __shared__ int sums[256];
  const int t = threadIdx.x;
  const int CH = (NN + 255) / 256;  // 196
  const int s0 = t * CH;
  const int s1 = (s0 + CH < NN) ? s0 + CH : NN;
  int sum = 0;
  for (int i = s0; i < s1; i++) sum += deg[i];
  sums[t] = sum;
  __syncthreads();
  const int mine = sum;
  for (int off = 1; off < 256; off <<= 1) {
    int add = (t >= off) ? sums[t - off] : 0;
    __syncthreads();
    sums[t] += add;
    __syncthreads();
  }
  int carry = sums[t] - mine;  // exclusive prefix
  for (int i = s0; i < s1; i++) { row_start[i] = carry; carry += deg[i]; }
  if (t == 255) row_start[NN] = carry;
}

__global__ void k_scatter(const int* __restrict__ src, const int* __restrict__ dst,
                          const int* __restrict__ row_start, int* __restrict__ cursor,
                          int* __restrict__ colidx) {
  int e = blockIdx.x * 256 + threadIdx.x;
  if (e < NE) {
    int s = src[e];
    int pos = row_start[s] + atomicAdd(&cursor[s], 1);
    colidx[pos] = dst[e];
  }
}

// ------------- attention (online softmax) + residual + LN1 -> out (=x1) ----
__global__ __launch_bounds__(256) void k_attn_ln1(
    const float* __restrict__ q, const float* __restrict__ k,
    const float* __restrict__ v, const float* __restrict__ x,
    const int* __restrict__ row_start, const int* __restrict__ colidx,
    const float* __restrict__ g1, const float* __restrict__ be1,
    float* __restrict__ out) {
  const int wv = threadIdx.x >> 6;
  const int lane = threadIdx.x & 63;
  const int node = blockIdx.x * 4 + wv;
  if (node >= NN) return;
  const float scale = 0.08838834764831845f;  // 128^-0.5
  float2 q2 = *(const float2*)&q[(size_t)node * ED + 2 * lane];
  const int r0 = row_start[node], r1 = row_start[node + 1];
  float m = -3.0e38f, l = 0.f;
  float ax = 0.f, ay = 0.f;
  for (int s = r0; s < r1; s++) {
    int c = colidx[s];
    float2 k2 = *(const float2*)&k[(size_t)c * ED + 2 * lane];
    float p = wave_sum(q2.x * k2.x + q2.y * k2.y);
    float a = p * scale;
    float nm = fmaxf(m, a);
    float corr = __expf(m - nm);
    float e = __expf(a - nm);
    l = l * corr + e;
    float2 v2 = *(const float2*)&v[(size_t)c * ED + 2 * lane];
    ax = ax * corr + e * v2.x;
    ay = ay * corr + e * v2.y;
    m = nm;
  }
  const float inv = (r1 > r0) ? 1.0f / l : 0.f;
  float2 xv = *(const float2*)&x[(size_t)node * ED + 2 * lane];
  float vx = xv.x + ax * inv;
  float vy = xv.y + ay * inv;
  float mean = wave_sum(vx + vy) * (1.f / ED);
  float dx = vx - mean, dy = vy - mean;
  float var = wave_sum(dx * dx + dy * dy) * (1.f / ED);
  float rstd = rsqrtf(var + 1e-5f);
  float2 gg = *(const float2*)&g1[2 * lane];
  float2 bb = *(const float2*)&be1[2 * lane];
  float2 o = make_float2(dx * rstd * gg.x + bb.x, dy * rstd * gg.y + bb.y);
  *(float2*)&out[(size_t)node * ED + 2 * lane] = o;
}

// ------------- FFN (relu(x1@W1+b1)@W2+b2) + residual + LN2, in-place on out
__global__ __launch_bounds__(256) void k_ffn_ln2(
    const float* __restrict__ x1, const float* __restrict__ W1,
    const float* __restrict__ b1, const float* __restrict__ W2,
    const float* __restrict__ b2, const float* __restrict__ g2,
    const float* __restrict__ be2, float* __restrict__ out) {
  __shared__ float xs[16][ED];       // 8 KB
  __shared__ float hs[16][FD + 4];   // 33 KB (pad 4 keeps float4 align, breaks bank stride)
  __shared__ float wt[16 * FD];      // 32 KB weight tile (W1 16x512 / W2 64x128)
  const int row0 = blockIdx.x * 16;
  const int tid = threadIdx.x;
  for (int idx = tid; idx < 16 * ED / 4; idx += 256) {
    int r = idx >> 5, c4 = (idx & 31) << 2;
    float4 val = make_float4(0.f, 0.f, 0.f, 0.f);
    if (row0 + r < NN) val = *(const float4*)&x1[(size_t)(row0 + r) * ED + c4];
    *(float4*)&xs[r][c4] = val;
  }
  // ---- GEMM1: h = relu(x@W1+b1) ----
  const int tx = tid & 127, ty = tid >> 7;
  float acc[8][4];
#pragma unroll
  for (int i = 0; i < 8; i++)
#pragma unroll
    for (int j = 0; j < 4; j++) acc[i][j] = 0.f;
  for (int k0 = 0; k0 < ED; k0 += 16) {
    __syncthreads();
    for (int idx = tid; idx < 16 * FD / 4; idx += 256) {
      int r = idx >> 7, c4 = (idx & 127) << 2;
      *(float4*)&wt[r * FD + c4] = *(const float4*)&W1[(size_t)(k0 + r) * FD + c4];
    }
    __syncthreads();
#pragma unroll
    for (int kk = 0; kk < 16; kk += 4) {
      float4 a4[8];
#pragma unroll
      for (int i = 0; i < 8; i++) a4[i] = *(const float4*)&xs[ty * 8 + i][k0 + kk];
#pragma unroll
      for (int u = 0; u < 4; u++) {
        float bb[4];
#pragma unroll
        for (int j = 0; j < 4; j++) bb[j] = wt[(kk + u) * FD + tx + 128 * j];
#pragma unroll
        for (int i = 0; i < 8; i++) {
          float a = (u == 0) ? a4[i].x : (u == 1) ? a4[i].y : (u == 2) ? a4[i].z : a4[i].w;
#pragma unroll
          for (int j = 0; j < 4; j++) acc[i][j] = fmaf(a, bb[j], acc[i][j]);
        }
      }
    }
  }
  float bb1[4];
#pragma unroll
  for (int j = 0; j < 4; j++) bb1[j] = b1[tx + 128 * j];
#pragma unroll
  for (int i = 0; i < 8; i++)
#pragma unroll
    for (int j = 0; j < 4; j++)
      hs[ty * 8 + i][tx + 128 * j] = fmaxf(acc[i][j] + bb1[j], 0.f);
  // ---- GEMM2: y = h@W2+b2 ----
  const int tx2 = tid & 63, ty2 = tid >> 6;
  float acc2[4][2];
#pragma unroll
  for (int i = 0; i < 4; i++) { acc2[i][0] = 0.f; acc2[i][1] = 0.f; }
  for (int k0 = 0; k0 < FD; k0 += 64) {
    __syncthreads();  // hs written (first iter) / wt readers done
    for (int idx = tid; idx < 64 * 128 / 4; idx += 256) {
      int r = idx >> 5, c4 = (idx & 31) << 2;
      *(float4*)&wt[r * 128 + c4] = *(const float4*)&W2[(size_t)(k0 + r) * 128 + c4];
    }
    __syncthreads();
#pragma unroll
    for (int kk = 0; kk < 64; kk += 4) {
      float4 a4[4];
#pragma unroll
      for (int i = 0; i < 4; i++) a4[i] = *(const float4*)&hs[ty2 * 4 + i][k0 + kk];
#pragma unroll
      for (int u = 0; u < 4; u++) {
        float b0 = wt[(kk + u) * 128 + tx2];
        float b1v = wt[(kk + u) * 128 + tx2 + 64];
#pragma unroll
        for (int i = 0; i < 4; i++) {
          float a = (u == 0) ? a4[i].x : (u == 1) ? a4[i].y : (u == 2) ? a4[i].z : a4[i].w;
          acc2[i][0] = fmaf(a, b0, acc2[i][0]);
          acc2[i][1] = fmaf(a, b1v, acc2[i][1]);
        }
      }
    }
  }
  // ---- residual + LN2 ----
  __syncthreads();                 // all hs reads done; reuse as ys[16][132]
  float* ys = &hs[0][0];
  const float bb2a = b2[tx2], bb2b = b2[tx2 + 64];
#pragma unroll
  for (int i = 0; i < 4; i++) {
    int r = ty2 * 4 + i;
    ys[r * 132 + tx2] = xs[r][tx2] + acc2[i][0] + bb2a;
    ys[r * 132 + tx2 + 64] = xs[r][tx2 + 64] + acc2[i][1] + bb2b;
  }
  __syncthreads();
  const int lane = tid & 63, wv = tid >> 6;
  float2 gg = *(const float2*)&g2[2 * lane];
  float2 bbe = *(const float2*)&be2[2 * lane];
#pragma unroll
  for (int rr = 0; rr < 4; rr++) {
    int r = wv * 4 + rr;
    float vx = ys[r * 132 + 2 * lane];
    float vy = ys[r * 132 + 2 * lane + 1];
    float mean = wave_sum(vx + vy) * (1.f / ED);
    float dx = vx - mean, dy = vy - mean;
    float var = wave_sum(dx * dx + dy * dy) * (1.f / ED);
    float rstd = rsqrtf(var + 1e-5f);
    int row = row0 + r;
    if (row < NN) {
      float2 o = make_float2(dx * rstd * gg.x + bbe.x, dy * rstd * gg.y + bbe.y);
      *(float2*)&out[(size_t)row * ED + 2 * lane] = o;
    }
  }
}

extern "C" void kernel_launch(void* const* d_in, const int* in_sizes, int n_in,
                              void* d_out, int out_size, void* d_ws, size_t ws_size,
                              hipStream_t stream) {
  const float* x = (const float*)d_in[0];
  const int* ei = (const int*)d_in[1];
  const float* W_qkv = (const float*)d_in[2];
  const float* b_qkv = (const float*)d_in[3];
  const float* W1 = (const float*)d_in[4];
  const float* b1 = (const float*)d_in[5];
  const float* W2 = (const float*)d_in[6];
  const float* b2 = (const float*)d_in[7];
  const float* g1 = (const float*)d_in[8];
  const float* be1 = (const float*)d_in[9];
  const float* g2 = (const float*)d_in[10];
  const float* be2 = (const float*)d_in[11];
  float* out = (float*)d_out;

  char* ws = (char*)d_ws;
  size_t off = 0;
  auto alloc = [&](size_t bytes) -> char* {
    char* p = ws + off;
    off = (off + bytes + 255) & ~(size_t)255;
    return p;
  };
  float* q = (float*)alloc(sizeof(float) * (size_t)NN * ED);
  float* k = (float*)alloc(sizeof(float) * (size_t)NN * ED);
  float* v = (float*)alloc(sizeof(float) * (size_t)NN * ED);
  int* deg = (int*)alloc(sizeof(int) * NN);
  int* cursor = (int*)alloc(sizeof(int) * NN);
  int* row_start = (int*)alloc(sizeof(int) * (NN + 1));
  int* colidx = (int*)alloc(sizeof(int) * NE);

  hipMemsetAsync(deg, 0, sizeof(int) * NN, stream);
  hipMemsetAsync(cursor, 0, sizeof(int) * NN, stream);

  k_gemm_qkv<<<(NN + 31) / 32, 256, 0, stream>>>(x, W_qkv, b_qkv, q, k, v);
  k_hist<<<(NE + 255) / 256, 256, 0, stream>>>(ei, deg);
  k_scan<<<1, 256, 0, stream>>>(deg, row_start);
  k_scatter<<<(NE + 255) / 256, 256, 0, stream>>>(ei, ei + NE, row_start, cursor, colidx);
  k_attn_ln1<<<NN / 4, 256, 0, stream>>>(q, k, v, x, row_start, colidx, g1, be1, out);
  k_ffn_ln2<<<(NN + 15) / 16, 256, 0, stream>>>(out, W1, b1, W2, b2, g2, be2, out);
}

// Round 2
// 536.737 us; speedup vs baseline: 1.4327x; 1.4327x over previous
//
#include <hip/hip_runtime.h>
#include <math.h>

#define NN 50000
#define NE 800000
#define ED 128
#define FD 512

typedef __attribute__((ext_vector_type(8))) short bf16x8;
typedef __attribute__((ext_vector_type(4))) float f32x4;

static __device__ __forceinline__ float wave_sum(float x) {
#pragma unroll
  for (int off = 32; off > 0; off >>= 1) x += __shfl_xor(x, off, 64);
  return x;
}

static __device__ __forceinline__ unsigned short f2bf(float f) {
  union { float f; unsigned u; } c; c.f = f;
  unsigned r = c.u + 0x7fffu + ((c.u >> 16) & 1u);
  return (unsigned short)(r >> 16);
}

static __device__ __forceinline__ float2 bfpair(unsigned u) {
  union { unsigned a; float f; } lo, hi;
  lo.a = u << 16; hi.a = u & 0xffff0000u;
  return make_float2(lo.f, hi.f);
}

// ---- one-time weight transpose + bf16 cast: W^T[n][k] layouts ----
__global__ void k_prep(const float* __restrict__ Wqkv, const float* __restrict__ W1,
                       const float* __restrict__ W2, unsigned short* __restrict__ WqkvT,
                       unsigned short* __restrict__ W1T, unsigned short* __restrict__ W2T) {
  int i = blockIdx.x * 256 + threadIdx.x;
  if (i < 384 * 128) { int n = i >> 7, k = i & 127; WqkvT[i] = f2bf(Wqkv[k * 384 + n]); }
  if (i < 512 * 128) { int n = i >> 7, k = i & 127; W1T[i] = f2bf(W1[k * 512 + n]); }
  if (i < 128 * 512) { int n = i >> 9, k = i & 511; W2T[i] = f2bf(W2[k * 128 + n]); }
}

// ---- QKV GEMM via MFMA: q,k,v written as bf16 ----
__global__ __launch_bounds__(256) void k_qkv_mfma(
    const float* __restrict__ X, const unsigned short* __restrict__ WqkvT,
    const float* __restrict__ B, unsigned short* __restrict__ q,
    unsigned short* __restrict__ k, unsigned short* __restrict__ v) {
  __shared__ unsigned short xs[32][136];  // pad 8 bf16: row stride 272B = 68 words (2-way free)
  const int row0 = blockIdx.x * 32;
  const int tid = threadIdx.x;
  for (int idx = tid; idx < 1024; idx += 256) {
    int r = idx >> 5, c4 = (idx & 31) << 2;
    float4 val = (row0 + r < NN) ? *(const float4*)&X[(size_t)(row0 + r) * ED + c4]
                                 : make_float4(0.f, 0.f, 0.f, 0.f);
    xs[r][c4] = f2bf(val.x); xs[r][c4 + 1] = f2bf(val.y);
    xs[r][c4 + 2] = f2bf(val.z); xs[r][c4 + 3] = f2bf(val.w);
  }
  __syncthreads();
  const int wv = tid >> 6, lane = tid & 63;
  const int mrow = (wv & 1) * 16 + (lane & 15);
  const int koff = (lane >> 4) * 8;
  bf16x8 a[4];
#pragma unroll
  for (int kb = 0; kb < 4; kb++) a[kb] = *(const bf16x8*)&xs[mrow][kb * 32 + koff];
  const int nbase = (wv >> 1) * 12;
  for (int nt = 0; nt < 12; nt++) {
    const int n0 = (nbase + nt) * 16;
    f32x4 acc = {0.f, 0.f, 0.f, 0.f};
#pragma unroll
    for (int kb = 0; kb < 4; kb++) {
      bf16x8 b = *(const bf16x8*)&WqkvT[(size_t)(n0 + (lane & 15)) * 128 + kb * 32 + koff];
      acc = __builtin_amdgcn_mfma_f32_16x16x32_bf16(a[kb], b, acc, 0, 0, 0);
    }
    const int col = n0 + (lane & 15);
    const float bias = B[col];
    unsigned short* dst = (col < 128) ? q : (col < 256) ? k : v;
    const int c = col & 127;
#pragma unroll
    for (int r = 0; r < 4; r++) {
      int row = row0 + (wv & 1) * 16 + (lane >> 4) * 4 + r;
      if (row < NN) dst[(size_t)row * ED + c] = f2bf(acc[r] + bias);
    }
  }
}

// ---------------- CSR build ----------------
__global__ void k_hist(const int* __restrict__ src, int* __restrict__ deg) {
  int e = blockIdx.x * 256 + threadIdx.x;
  if (e < NE) atomicAdd(&deg[src[e]], 1);
}

__global__ void k_scan(const int* __restrict__ deg, int* __restrict__ row_start) {
  __shared__ int sums[256];
  const int t = threadIdx.x;
  const int CH = (NN + 255) / 256;
  const int s0 = t * CH;
  const int s1 = (s0 + CH < NN) ? s0 + CH : NN;
  int sum = 0;
  for (int i = s0; i < s1; i++) sum += deg[i];
  sums[t] = sum;
  __syncthreads();
  const int mine = sum;
  for (int off = 1; off < 256; off <<= 1) {
    int add = (t >= off) ? sums[t - off] : 0;
    __syncthreads();
    sums[t] += add;
    __syncthreads();
  }
  int carry = sums[t] - mine;
  for (int i = s0; i < s1; i++) { row_start[i] = carry; carry += deg[i]; }
  if (t == 255) row_start[NN] = carry;
}

__global__ void k_scatter(const int* __restrict__ src, const int* __restrict__ dst,
                          const int* __restrict__ row_start, int* __restrict__ cursor,
                          int* __restrict__ colidx) {
  int e = blockIdx.x * 256 + threadIdx.x;
  if (e < NE) {
    int s = src[e];
    int pos = row_start[s] + atomicAdd(&cursor[s], 1);
    colidx[pos] = dst[e];
  }
}

// ---- attention (online softmax, bf16 q/k/v gathers) + residual + LN1 ----
__global__ __launch_bounds__(256) void k_attn_ln1(
    const unsigned short* __restrict__ q, const unsigned short* __restrict__ k,
    const unsigned short* __restrict__ v, const float* __restrict__ x,
    const int* __restrict__ row_start, const int* __restrict__ colidx,
    const float* __restrict__ g1, const float* __restrict__ be1,
    float* __restrict__ out) {
  const int wv = threadIdx.x >> 6;
  const int lane = threadIdx.x & 63;
  const int node = blockIdx.x * 4 + wv;
  if (node >= NN) return;
  const float scale = 0.08838834764831845f;  // 128^-0.5
  float2 q2 = bfpair(*(const unsigned*)&q[(size_t)node * ED + 2 * lane]);
  const int r0 = row_start[node], r1 = row_start[node + 1];
  float m = -3.0e38f, l = 0.f, ax = 0.f, ay = 0.f;
  for (int s = r0; s < r1; s++) {
    int c = colidx[s];
    float2 k2 = bfpair(*(const unsigned*)&k[(size_t)c * ED + 2 * lane]);
    float p = wave_sum(q2.x * k2.x + q2.y * k2.y);
    float a = p * scale;
    float nm = fmaxf(m, a);
    float corr = __expf(m - nm);
    float e = __expf(a - nm);
    l = l * corr + e;
    float2 v2 = bfpair(*(const unsigned*)&v[(size_t)c * ED + 2 * lane]);
    ax = ax * corr + e * v2.x;
    ay = ay * corr + e * v2.y;
    m = nm;
  }
  const float inv = (r1 > r0) ? 1.0f / l : 0.f;
  float2 xv = *(const float2*)&x[(size_t)node * ED + 2 * lane];
  float vx = xv.x + ax * inv;
  float vy = xv.y + ay * inv;
  float mean = wave_sum(vx + vy) * (1.f / ED);
  float dx = vx - mean, dy = vy - mean;
  float var = wave_sum(dx * dx + dy * dy) * (1.f / ED);
  float rstd = rsqrtf(var + 1e-5f);
  float2 gg = *(const float2*)&g1[2 * lane];
  float2 bb = *(const float2*)&be1[2 * lane];
  float2 o = make_float2(dx * rstd * gg.x + bb.x, dy * rstd * gg.y + bb.y);
  *(float2*)&out[(size_t)node * ED + 2 * lane] = o;
}

// ---- FFN via MFMA + residual + LN2, in-place on out ----
__global__ __launch_bounds__(256) void k_ffn_ln2(
    const unsigned short* __restrict__ W1T, const float* __restrict__ b1,
    const unsigned short* __restrict__ W2T, const float* __restrict__ b2,
    const float* __restrict__ g2, const float* __restrict__ be2,
    float* __restrict__ out) {
  __shared__ unsigned short xs[32][136];  // 8.7 KB
  __shared__ unsigned short hs[32][520];  // 33.3 KB; later aliased as ys f32[32][132]
  float* ys = (float*)&hs[0][0];
  const int row0 = blockIdx.x * 32;
  const int tid = threadIdx.x;
  for (int idx = tid; idx < 1024; idx += 256) {
    int r = idx >> 5, c4 = (idx & 31) << 2;
    float4 val = (row0 + r < NN) ? *(const float4*)&out[(size_t)(row0 + r) * ED + c4]
                                 : make_float4(0.f, 0.f, 0.f, 0.f);
    xs[r][c4] = f2bf(val.x); xs[r][c4 + 1] = f2bf(val.y);
    xs[r][c4 + 2] = f2bf(val.z); xs[r][c4 + 3] = f2bf(val.w);
  }
  __syncthreads();
  const int wv = tid >> 6, lane = tid & 63;
  const int mt = wv & 1;
  const int mrow = mt * 16 + (lane & 15);
  const int koff = (lane >> 4) * 8;
  // ---- GEMM1: h = relu(x1 @ W1 + b1), h -> LDS bf16 ----
  bf16x8 a1[4];
#pragma unroll
  for (int kb = 0; kb < 4; kb++) a1[kb] = *(const bf16x8*)&xs[mrow][kb * 32 + koff];
  const int nbase1 = (wv >> 1) * 16;
  for (int nt = 0; nt < 16; nt++) {
    const int n0 = (nbase1 + nt) * 16;
    f32x4 acc = {0.f, 0.f, 0.f, 0.f};
#pragma unroll
    for (int kb = 0; kb < 4; kb++) {
      bf16x8 b = *(const bf16x8*)&W1T[(size_t)(n0 + (lane & 15)) * 128 + kb * 32 + koff];
      acc = __builtin_amdgcn_mfma_f32_16x16x32_bf16(a1[kb], b, acc, 0, 0, 0);
    }
    const int col = n0 + (lane & 15);
    const float bias = b1[col];
#pragma unroll
    for (int r = 0; r < 4; r++) {
      int row = mt * 16 + (lane >> 4) * 4 + r;
      hs[row][col] = f2bf(fmaxf(acc[r] + bias, 0.f));
    }
  }
  __syncthreads();
  // ---- GEMM2: y = h @ W2 + b2 ----
  f32x4 acc2[4];
#pragma unroll
  for (int i = 0; i < 4; i++) acc2[i] = (f32x4){0.f, 0.f, 0.f, 0.f};
  const int nbase2 = (wv >> 1) * 4;
  for (int kb = 0; kb < 16; kb++) {
    bf16x8 a = *(const bf16x8*)&hs[mrow][kb * 32 + koff];
#pragma unroll
    for (int nt = 0; nt < 4; nt++) {
      const int n0 = (nbase2 + nt) * 16;
      bf16x8 b = *(const bf16x8*)&W2T[(size_t)(n0 + (lane & 15)) * 512 + kb * 32 + koff];
      acc2[nt] = __builtin_amdgcn_mfma_f32_16x16x32_bf16(a, b, acc2[nt], 0, 0, 0);
    }
  }
  __syncthreads();  // all hs reads done -> safe to alias as ys
#pragma unroll
  for (int nt = 0; nt < 4; nt++) {
    const int col = (nbase2 + nt) * 16 + (lane & 15);
    const float bias = b2[col];
#pragma unroll
    for (int r = 0; r < 4; r++) {
      int row = mt * 16 + (lane >> 4) * 4 + r;
      ys[row * 132 + col] = acc2[nt][r] + bias;
    }
  }
  __syncthreads();
  // ---- residual + LN2 ----
  float2 gg = *(const float2*)&g2[2 * lane];
  float2 bbe = *(const float2*)&be2[2 * lane];
#pragma unroll
  for (int rr = 0; rr < 8; rr++) {
    const int r = wv * 8 + rr;
    const int row = row0 + r;
    float vx = ys[r * 132 + 2 * lane];
    float vy = ys[r * 132 + 2 * lane + 1];
    if (row < NN) {
      float2 xr = *(const float2*)&out[(size_t)row * ED + 2 * lane];
      vx += xr.x; vy += xr.y;
    }
    float mean = wave_sum(vx + vy) * (1.f / ED);
    float dx = vx - mean, dy = vy - mean;
    float var = wave_sum(dx * dx + dy * dy) * (1.f / ED);
    float rstd = rsqrtf(var + 1e-5f);
    if (row < NN) {
      float2 o = make_float2(dx * rstd * gg.x + bbe.x, dy * rstd * gg.y + bbe.y);
      *(float2*)&out[(size_t)row * ED + 2 * lane] = o;
    }
  }
}

extern "C" void kernel_launch(void* const* d_in, const int* in_sizes, int n_in,
                              void* d_out, int out_size, void* d_ws, size_t ws_size,
                              hipStream_t stream) {
  const float* x = (const float*)d_in[0];
  const int* ei = (const int*)d_in[1];
  const float* W_qkv = (const float*)d_in[2];
  const float* b_qkv = (const float*)d_in[3];
  const float* W1 = (const float*)d_in[4];
  const float* b1 = (const float*)d_in[5];
  const float* W2 = (const float*)d_in[6];
  const float* b2 = (const float*)d_in[7];
  const float* g1 = (const float*)d_in[8];
  const float* be1 = (const float*)d_in[9];
  const float* g2 = (const float*)d_in[10];
  const float* be2 = (const float*)d_in[11];
  float* out = (float*)d_out;

  char* ws = (char*)d_ws;
  size_t off = 0;
  auto alloc = [&](size_t bytes) -> char* {
    char* p = ws + off;
    off = (off + bytes + 255) & ~(size_t)255;
    return p;
  };
  unsigned short* q = (unsigned short*)alloc(2 * (size_t)NN * ED);
  unsigned short* k = (unsigned short*)alloc(2 * (size_t)NN * ED);
  unsigned short* v = (unsigned short*)alloc(2 * (size_t)NN * ED);
  unsigned short* WqkvT = (unsigned short*)alloc(2 * 384 * 128);
  unsigned short* W1T = (unsigned short*)alloc(2 * 512 * 128);
  unsigned short* W2T = (unsigned short*)alloc(2 * 128 * 512);
  int* deg = (int*)alloc(sizeof(int) * NN);
  int* cursor = (int*)alloc(sizeof(int) * NN);
  int* row_start = (int*)alloc(sizeof(int) * (NN + 1));
  int* colidx = (int*)alloc(sizeof(int) * NE);

  hipMemsetAsync(deg, 0, sizeof(int) * NN, stream);
  hipMemsetAsync(cursor, 0, sizeof(int) * NN, stream);

  k_prep<<<256, 256, 0, stream>>>(W_qkv, W1, W2, WqkvT, W1T, W2T);
  k_qkv_mfma<<<(NN + 31) / 32, 256, 0, stream>>>(x, WqkvT, b_qkv, q, k, v);
  k_hist<<<(NE + 255) / 256, 256, 0, stream>>>(ei, deg);
  k_scan<<<1, 256, 0, stream>>>(deg, row_start);
  k_scatter<<<(NE + 255) / 256, 256, 0, stream>>>(ei, ei + NE, row_start, cursor, colidx);
  k_attn_ln1<<<NN / 4, 256, 0, stream>>>(q, k, v, x, row_start, colidx, g1, be1, out);
  k_ffn_ln2<<<(NN + 31) / 32, 256, 0, stream>>>(W1T, b1, W2T, b2, g2, be2, out);
}

// Round 3
// 499.327 us; speedup vs baseline: 1.5401x; 1.0749x over previous
//
#include <hip/hip_runtime.h>
#include <math.h>

#define NN 50000
#define NE 800000
#define ED 128
#define FD 512

typedef __attribute__((ext_vector_type(8))) short bf16x8;
typedef __attribute__((ext_vector_type(4))) float f32x4;

static __device__ __forceinline__ float wave_sum(float x) {
#pragma unroll
  for (int off = 32; off > 0; off >>= 1) x += __shfl_xor(x, off, 64);
  return x;
}

static __device__ __forceinline__ unsigned short f2bf(float f) {
  union { float f; unsigned u; } c; c.f = f;
  unsigned r = c.u + 0x7fffu + ((c.u >> 16) & 1u);
  return (unsigned short)(r >> 16);
}

static __device__ __forceinline__ float2 bfpair(unsigned u) {
  union { unsigned a; float f; } lo, hi;
  lo.a = u << 16; hi.a = u & 0xffff0000u;
  return make_float2(lo.f, hi.f);
}

// ---- one-time weight transpose + bf16 cast: W^T[n][k] layouts ----
__global__ void k_prep(const float* __restrict__ Wqkv, const float* __restrict__ W1,
                       const float* __restrict__ W2, unsigned short* __restrict__ WqkvT,
                       unsigned short* __restrict__ W1T, unsigned short* __restrict__ W2T) {
  int i = blockIdx.x * 256 + threadIdx.x;
  if (i < 384 * 128) { int n = i >> 7, k = i & 127; WqkvT[i] = f2bf(Wqkv[k * 384 + n]); }
  if (i < 512 * 128) { int n = i >> 7, k = i & 127; W1T[i] = f2bf(W1[k * 512 + n]); }
  if (i < 128 * 512) { int n = i >> 9, k = i & 511; W2T[i] = f2bf(W2[k * 128 + n]); }
}

// ---- QKV GEMM via MFMA: q,k,v written as bf16 ----
__global__ __launch_bounds__(256) void k_qkv_mfma(
    const float* __restrict__ X, const unsigned short* __restrict__ WqkvT,
    const float* __restrict__ B, unsigned short* __restrict__ q,
    unsigned short* __restrict__ k, unsigned short* __restrict__ v) {
  __shared__ unsigned short xs[32][136];
  const int row0 = blockIdx.x * 32;
  const int tid = threadIdx.x;
  for (int idx = tid; idx < 1024; idx += 256) {
    int r = idx >> 5, c4 = (idx & 31) << 2;
    float4 val = (row0 + r < NN) ? *(const float4*)&X[(size_t)(row0 + r) * ED + c4]
                                 : make_float4(0.f, 0.f, 0.f, 0.f);
    xs[r][c4] = f2bf(val.x); xs[r][c4 + 1] = f2bf(val.y);
    xs[r][c4 + 2] = f2bf(val.z); xs[r][c4 + 3] = f2bf(val.w);
  }
  __syncthreads();
  const int wv = tid >> 6, lane = tid & 63;
  const int mrow = (wv & 1) * 16 + (lane & 15);
  const int koff = (lane >> 4) * 8;
  bf16x8 a[4];
#pragma unroll
  for (int kb = 0; kb < 4; kb++) a[kb] = *(const bf16x8*)&xs[mrow][kb * 32 + koff];
  const int nbase = (wv >> 1) * 12;
  for (int nt = 0; nt < 12; nt++) {
    const int n0 = (nbase + nt) * 16;
    f32x4 acc = {0.f, 0.f, 0.f, 0.f};
#pragma unroll
    for (int kb = 0; kb < 4; kb++) {
      bf16x8 b = *(const bf16x8*)&WqkvT[(size_t)(n0 + (lane & 15)) * 128 + kb * 32 + koff];
      acc = __builtin_amdgcn_mfma_f32_16x16x32_bf16(a[kb], b, acc, 0, 0, 0);
    }
    const int col = n0 + (lane & 15);
    const float bias = B[col];
    unsigned short* dst = (col < 128) ? q : (col < 256) ? k : v;
    const int c = col & 127;
#pragma unroll
    for (int r = 0; r < 4; r++) {
      int row = row0 + (wv & 1) * 16 + (lane >> 4) * 4 + r;
      if (row < NN) dst[(size_t)row * ED + c] = f2bf(acc[r] + bias);
    }
  }
}

// ---------------- CSR build ----------------
__global__ void k_hist(const int* __restrict__ src, int* __restrict__ deg) {
  int e = blockIdx.x * 256 + threadIdx.x;
  if (e < NE) atomicAdd(&deg[src[e]], 1);
}

__global__ void k_scan(const int* __restrict__ deg, int* __restrict__ row_start) {
  __shared__ int sums[1024];
  const int t = threadIdx.x;
  const int CH = (NN + 1023) / 1024;  // 49
  const int s0 = t * CH;
  const int s1 = (s0 + CH < NN) ? s0 + CH : NN;
  int sum = 0;
  for (int i = s0; i < s1; i++) sum += deg[i];
  sums[t] = sum;
  __syncthreads();
  const int mine = sum;
  for (int off = 1; off < 1024; off <<= 1) {
    int add = (t >= off) ? sums[t - off] : 0;
    __syncthreads();
    sums[t] += add;
    __syncthreads();
  }
  int carry = sums[t] - mine;
  for (int i = s0; i < s1; i++) { row_start[i] = carry; carry += deg[i]; }
  if (t == 1023) row_start[NN] = carry;
}

__global__ void k_scatter(const int* __restrict__ src, const int* __restrict__ dst,
                          const int* __restrict__ row_start, int* __restrict__ cursor,
                          int* __restrict__ colidx) {
  int e = blockIdx.x * 256 + threadIdx.x;
  if (e < NE) {
    int s = src[e];
    int pos = row_start[s] + atomicAdd(&cursor[s], 1);
    colidx[pos] = dst[e];
  }
}

// ---- attention: chunked two-phase online softmax ----
template <bool FULL>
static __device__ __forceinline__ void attn_chunk(
    int base, int cnt, int lane, int grp, int gl, const float* qf,
    const unsigned short* __restrict__ k, const unsigned short* __restrict__ v,
    const int* __restrict__ colidx, int* sc, float* sl, float* se,
    float& m, float& l, float& ax, float& ay) {
  const int C = FULL ? 16 : cnt;
  if (lane < C) sc[lane] = colidx[base + lane];
  // phase A: 4 lane-groups, one edge each, 4 rounds
#pragma unroll
  for (int it = 0; it < 4; it++) {
    const int t = it * 4 + grp;
    float dot = 0.f;
    if (FULL || t < C) {
      const int c = sc[t];
      uint4 kw = *(const uint4*)&k[(size_t)c * ED + gl * 8];
      float2 p0 = bfpair(kw.x), p1 = bfpair(kw.y), p2 = bfpair(kw.z), p3 = bfpair(kw.w);
      dot = qf[0] * p0.x + qf[1] * p0.y + qf[2] * p1.x + qf[3] * p1.y +
            qf[4] * p2.x + qf[5] * p2.y + qf[6] * p3.x + qf[7] * p3.y;
    }
    dot += __shfl_xor(dot, 1, 64);
    dot += __shfl_xor(dot, 2, 64);
    dot += __shfl_xor(dot, 4, 64);
    dot += __shfl_xor(dot, 8, 64);
    if (gl == 0 && (FULL || t < C))
      sl[t] = dot * 0.08838834764831845f;  // 128^-0.5
  }
  // chunk max, replicated per 16-lane group
  float lg = (FULL || (lane & 15) < C) ? sl[lane & 15] : -3.0e38f;
  lg = fmaxf(lg, __shfl_xor(lg, 1, 64));
  lg = fmaxf(lg, __shfl_xor(lg, 2, 64));
  lg = fmaxf(lg, __shfl_xor(lg, 4, 64));
  lg = fmaxf(lg, __shfl_xor(lg, 8, 64));
  const float nm = fmaxf(m, lg);
  const float corr = __expf(m - nm);
  if (lane < 16) se[lane] = (FULL || lane < C) ? __expf(sl[lane] - nm) : 0.f;
  float ev = (FULL || (lane & 15) < C) ? se[lane & 15] : 0.f;
  ev += __shfl_xor(ev, 1, 64);
  ev += __shfl_xor(ev, 2, 64);
  ev += __shfl_xor(ev, 4, 64);
  ev += __shfl_xor(ev, 8, 64);
  l = l * corr + ev;
  ax *= corr; ay *= corr;
  m = nm;
  // phase B: independent weighted-V gathers
  if (FULL) {
#pragma unroll
    for (int t = 0; t < 16; t++) {
      const int c = sc[t];
      const float e = se[t];
      float2 v2 = bfpair(*(const unsigned*)&v[(size_t)c * ED + 2 * lane]);
      ax = fmaf(e, v2.x, ax);
      ay = fmaf(e, v2.y, ay);
    }
  } else {
    for (int t = 0; t < cnt; t++) {
      const int c = sc[t];
      const float e = se[t];
      float2 v2 = bfpair(*(const unsigned*)&v[(size_t)c * ED + 2 * lane]);
      ax = fmaf(e, v2.x, ax);
      ay = fmaf(e, v2.y, ay);
    }
  }
}

__global__ __launch_bounds__(256) void k_attn_ln1(
    const unsigned short* __restrict__ q, const unsigned short* __restrict__ k,
    const unsigned short* __restrict__ v, const float* __restrict__ x,
    const int* __restrict__ row_start, const int* __restrict__ colidx,
    const float* __restrict__ g1, const float* __restrict__ be1,
    float* __restrict__ out) {
  const int wv = threadIdx.x >> 6;
  const int lane = threadIdx.x & 63;
  const int grp = lane >> 4, gl = lane & 15;
  const int node = blockIdx.x * 4 + wv;  // grid exact: NN % 4 == 0
  __shared__ int scol[4][16];
  __shared__ float slog[4][16];
  __shared__ float sexp[4][16];
  int* sc = scol[wv]; float* sl = slog[wv]; float* se = sexp[wv];

  float qf[8];
  {
    uint4 qw = *(const uint4*)&q[(size_t)node * ED + gl * 8];
    float2 p0 = bfpair(qw.x), p1 = bfpair(qw.y), p2 = bfpair(qw.z), p3 = bfpair(qw.w);
    qf[0] = p0.x; qf[1] = p0.y; qf[2] = p1.x; qf[3] = p1.y;
    qf[4] = p2.x; qf[5] = p2.y; qf[6] = p3.x; qf[7] = p3.y;
  }
  const int r0 = row_start[node], r1 = row_start[node + 1];
  float m = -3.0e38f, l = 0.f, ax = 0.f, ay = 0.f;
  int base = r0;
  for (; base + 16 <= r1; base += 16)
    attn_chunk<true>(base, 16, lane, grp, gl, qf, k, v, colidx, sc, sl, se, m, l, ax, ay);
  if (base < r1)
    attn_chunk<false>(base, r1 - base, lane, grp, gl, qf, k, v, colidx, sc, sl, se, m, l, ax, ay);

  const float inv = (r1 > r0) ? 1.0f / l : 0.f;
  float2 xv = *(const float2*)&x[(size_t)node * ED + 2 * lane];
  float vx = xv.x + ax * inv;
  float vy = xv.y + ay * inv;
  float mean = wave_sum(vx + vy) * (1.f / ED);
  float dx = vx - mean, dy = vy - mean;
  float var = wave_sum(dx * dx + dy * dy) * (1.f / ED);
  float rstd = rsqrtf(var + 1e-5f);
  float2 gg = *(const float2*)&g1[2 * lane];
  float2 bb = *(const float2*)&be1[2 * lane];
  float2 o = make_float2(dx * rstd * gg.x + bb.x, dy * rstd * gg.y + bb.y);
  *(float2*)&out[(size_t)node * ED + 2 * lane] = o;
}

// ---- FFN via MFMA + residual + LN2, in-place on out ----
__global__ __launch_bounds__(256) void k_ffn_ln2(
    const float* __restrict__ x1, const unsigned short* __restrict__ W1T,
    const float* __restrict__ b1, const unsigned short* __restrict__ W2T,
    const float* __restrict__ b2, const float* __restrict__ g2,
    const float* __restrict__ be2, float* __restrict__ out) {
  __shared__ unsigned short xs[32][136];
  __shared__ unsigned short hs[32][520];  // later aliased as ys f32[32][132]
  float* ys = (float*)&hs[0][0];
  const int row0 = blockIdx.x * 32;
  const int tid = threadIdx.x;
  for (int idx = tid; idx < 1024; idx += 256) {
    int r = idx >> 5, c4 = (idx & 31) << 2;
    float4 val = (row0 + r < NN) ? *(const float4*)&x1[(size_t)(row0 + r) * ED + c4]
                                 : make_float4(0.f, 0.f, 0.f, 0.f);
    xs[r][c4] = f2bf(val.x); xs[r][c4 + 1] = f2bf(val.y);
    xs[r][c4 + 2] = f2bf(val.z); xs[r][c4 + 3] = f2bf(val.w);
  }
  __syncthreads();
  const int wv = tid >> 6, lane = tid & 63;
  const int mt = wv & 1;
  const int mrow = mt * 16 + (lane & 15);
  const int koff = (lane >> 4) * 8;
  bf16x8 a1[4];
#pragma unroll
  for (int kb = 0; kb < 4; kb++) a1[kb] = *(const bf16x8*)&xs[mrow][kb * 32 + koff];
  const int nbase1 = (wv >> 1) * 16;
  for (int nt = 0; nt < 16; nt++) {
    const int n0 = (nbase1 + nt) * 16;
    f32x4 acc = {0.f, 0.f, 0.f, 0.f};
#pragma unroll
    for (int kb = 0; kb < 4; kb++) {
      bf16x8 b = *(const bf16x8*)&W1T[(size_t)(n0 + (lane & 15)) * 128 + kb * 32 + koff];
      acc = __builtin_amdgcn_mfma_f32_16x16x32_bf16(a1[kb], b, acc, 0, 0, 0);
    }
    const int col = n0 + (lane & 15);
    const float bias = b1[col];
#pragma unroll
    for (int r = 0; r < 4; r++) {
      int row = mt * 16 + (lane >> 4) * 4 + r;
      hs[row][col] = f2bf(fmaxf(acc[r] + bias, 0.f));
    }
  }
  __syncthreads();
  f32x4 acc2[4];
#pragma unroll
  for (int i = 0; i < 4; i++) acc2[i] = (f32x4){0.f, 0.f, 0.f, 0.f};
  const int nbase2 = (wv >> 1) * 4;
  for (int kb = 0; kb < 16; kb++) {
    bf16x8 a = *(const bf16x8*)&hs[mrow][kb * 32 + koff];
#pragma unroll
    for (int nt = 0; nt < 4; nt++) {
      const int n0 = (nbase2 + nt) * 16;
      bf16x8 b = *(const bf16x8*)&W2T[(size_t)(n0 + (lane & 15)) * 512 + kb * 32 + koff];
      acc2[nt] = __builtin_amdgcn_mfma_f32_16x16x32_bf16(a, b, acc2[nt], 0, 0, 0);
    }
  }
  __syncthreads();  // all hs reads done -> safe to alias as ys
#pragma unroll
  for (int nt = 0; nt < 4; nt++) {
    const int col = (nbase2 + nt) * 16 + (lane & 15);
    const float bias = b2[col];
#pragma unroll
    for (int r = 0; r < 4; r++) {
      int row = mt * 16 + (lane >> 4) * 4 + r;
      ys[row * 132 + col] = acc2[nt][r] + bias;
    }
  }
  __syncthreads();
  float2 gg = *(const float2*)&g2[2 * lane];
  float2 bbe = *(const float2*)&be2[2 * lane];
#pragma unroll
  for (int rr = 0; rr < 8; rr++) {
    const int r = wv * 8 + rr;
    const int row = row0 + r;
    float vx = ys[r * 132 + 2 * lane];
    float vy = ys[r * 132 + 2 * lane + 1];
    if (row < NN) {
      float2 xr = *(const float2*)&out[(size_t)row * ED + 2 * lane];
      vx += xr.x; vy += xr.y;
    }
    float mean = wave_sum(vx + vy) * (1.f / ED);
    float dx = vx - mean, dy = vy - mean;
    float var = wave_sum(dx * dx + dy * dy) * (1.f / ED);
    float rstd = rsqrtf(var + 1e-5f);
    if (row < NN) {
      float2 o = make_float2(dx * rstd * gg.x + bbe.x, dy * rstd * gg.y + bbe.y);
      *(float2*)&out[(size_t)row * ED + 2 * lane] = o;
    }
  }
}

extern "C" void kernel_launch(void* const* d_in, const int* in_sizes, int n_in,
                              void* d_out, int out_size, void* d_ws, size_t ws_size,
                              hipStream_t stream) {
  const float* x = (const float*)d_in[0];
  const int* ei = (const int*)d_in[1];
  const float* W_qkv = (const float*)d_in[2];
  const float* b_qkv = (const float*)d_in[3];
  const float* W1 = (const float*)d_in[4];
  const float* b1 = (const float*)d_in[5];
  const float* W2 = (const float*)d_in[6];
  const float* b2 = (const float*)d_in[7];
  const float* g1 = (const float*)d_in[8];
  const float* be1 = (const float*)d_in[9];
  const float* g2 = (const float*)d_in[10];
  const float* be2 = (const float*)d_in[11];
  float* out = (float*)d_out;

  char* ws = (char*)d_ws;
  size_t off = 0;
  auto alloc = [&](size_t bytes) -> char* {
    char* p = ws + off;
    off = (off + bytes + 255) & ~(size_t)255;
    return p;
  };
  unsigned short* q = (unsigned short*)alloc(2 * (size_t)NN * ED);
  unsigned short* k = (unsigned short*)alloc(2 * (size_t)NN * ED);
  unsigned short* v = (unsigned short*)alloc(2 * (size_t)NN * ED);
  unsigned short* WqkvT = (unsigned short*)alloc(2 * 384 * 128);
  unsigned short* W1T = (unsigned short*)alloc(2 * 512 * 128);
  unsigned short* W2T = (unsigned short*)alloc(2 * 128 * 512);
  int* deg = (int*)alloc(sizeof(int) * NN);
  int* cursor = (int*)alloc(sizeof(int) * NN);
  int* row_start = (int*)alloc(sizeof(int) * (NN + 1));
  int* colidx = (int*)alloc(sizeof(int) * NE);

  hipMemsetAsync(deg, 0, sizeof(int) * NN, stream);
  hipMemsetAsync(cursor, 0, sizeof(int) * NN, stream);

  k_prep<<<256, 256, 0, stream>>>(W_qkv, W1, W2, WqkvT, W1T, W2T);
  k_qkv_mfma<<<(NN + 31) / 32, 256, 0, stream>>>(x, WqkvT, b_qkv, q, k, v);
  k_hist<<<(NE + 255) / 256, 256, 0, stream>>>(ei, deg);
  k_scan<<<1, 1024, 0, stream>>>(deg, row_start);
  k_scatter<<<(NE + 255) / 256, 256, 0, stream>>>(ei, ei + NE, row_start, cursor, colidx);
  k_attn_ln1<<<NN / 4, 256, 0, stream>>>(q, k, v, x, row_start, colidx, g1, be1, out);
  k_ffn_ln2<<<(NN + 31) / 32, 256, 0, stream>>>(out, W1T, b1, W2T, b2, g2, be2, out);
}